// Round 10
// baseline (514.057 us; speedup 1.0000x reference)
//
#include <hip/hip_runtime.h>

constexpr int TT = 512;    // timesteps
constexpr int BB = 256;    // batch
constexpr int HH = 128;    // hidden = embed
constexpr int VV = 32000;  // vocab

typedef _Float16 h2 __attribute__((ext_vector_type(2)));
typedef _Float16 f16x4 __attribute__((ext_vector_type(4)));
typedef _Float16 f16x8 __attribute__((ext_vector_type(8)));
typedef float f32x4 __attribute__((ext_vector_type(4)));

struct __align__(16) H2x4 { h2 a, b, c, d; };

__device__ __forceinline__ h2 pkrtz(float a, float b) {
  return __builtin_bit_cast(h2, __builtin_amdgcn_cvt_pkrtz(a, b));
}
__device__ __forceinline__ float fexp2(float x) {
  return __builtin_amdgcn_exp2f(x);
}
__device__ __forceinline__ float frcp(float x) {
  return __builtin_amdgcn_rcpf(x);
}
__device__ __forceinline__ float fdot2(h2 a, h2 b, float c) {
  return __builtin_amdgcn_fdot2(a, b, c, false);
}
// quad_perm DPP: 0xB1 = [1,0,3,2] (xor1), 0x4E = [2,3,0,1] (xor2)
template <int CTRL>
__device__ __forceinline__ float qmov(float v) {
  return __builtin_bit_cast(
      float, __builtin_amdgcn_mov_dpp(__builtin_bit_cast(int, v), CTRL, 0xf,
                                      0xf, true));
}
// DPP row_ror:1 (ctrl 0x121): rotate within each 16-lane row by one lane.
__device__ __forceinline__ int ror1_i(int v) {
  return __builtin_amdgcn_mov_dpp(v, 0x121, 0xf, 0xf, true);
}
__device__ __forceinline__ h2 ror1_h(h2 v) {
  return __builtin_bit_cast(h2, ror1_i(__builtin_bit_cast(int, v)));
}

// Gate pre-scales folded into weights so activations are exp2-direct:
//   g in {i,f,o}: a = -x*log2e  -> exp2(a) = e^-x   (sigmoid via rcp)
//   g == c      : a = 2x*log2e  -> exp2(a) = e^{2x} (tanh via rcp)
constexpr float SC_SIG = -1.4426950408889634f;
constexpr float SC_TANH = 2.8853900817779268f;

// Fused prep: blocks [0,512) pack gate weights into Wct[n=4u+g][k] f16
// (k 0..127 e-part, 128..255 h-part) + bcat[n] (scaled bias); blocks
// [512, 512+125) transpose Wout fp32 -> Wt[v][k] f16. One launch.
__global__ __launch_bounds__(256, 4) void prep(
    const float* __restrict__ Wi, const float* __restrict__ bi,
    const float* __restrict__ Wf, const float* __restrict__ bf,
    const float* __restrict__ Wc, const float* __restrict__ bc,
    const float* __restrict__ Wo, const float* __restrict__ bo,
    _Float16* __restrict__ Wct, float* __restrict__ bcat,
    const float* __restrict__ Wout, _Float16* __restrict__ Wt) {
  if (blockIdx.x < 512) {
    const int n = blockIdx.x;  // 0..511
    const int g = n & 3;
    const int u = n >> 2;
    const float* Wg = (g == 0) ? Wi : (g == 1) ? Wf : (g == 2) ? Wc : Wo;
    const float* bg = (g == 0) ? bi : (g == 1) ? bf : (g == 2) ? bc : bo;
    const float sc = (g == 2) ? SC_TANH : SC_SIG;
    const int k = threadIdx.x;  // 0..255
    Wct[(size_t)n * 256 + k] = (_Float16)(Wg[(size_t)k * HH + u] * sc);
    if (k == 0) bcat[n] = bg[u] * sc;
  } else {
    const int v = (blockIdx.x - 512) * 256 + threadIdx.x;
#pragma unroll 1
    for (int kc = 0; kc < 16; ++kc) {
      float f[8];
#pragma unroll
      for (int i = 0; i < 8; ++i) f[i] = Wout[(size_t)(kc * 8 + i) * VV + v];
      H2x4 q;
      q.a = pkrtz(f[0], f[1]);
      q.b = pkrtz(f[2], f[3]);
      q.c = pkrtz(f[4], f[5]);
      q.d = pkrtz(f[6], f[7]);
      *(H2x4*)(Wt + (size_t)v * HH + kc * 8) = q;
    }
  }
}

// One block per batch element (256 blocks), 512 threads = 8 waves, 2/SIMD.
// R10: ROTOR DOT. Insight from R4/R6/R8/R9 regression set: the per-CU LDS
// pipe (~11 cyc/ds-op, shared by 4 SIMDs) was the hidden bottleneck —
// R6's 18 ds-ops/wave/step = ~1580 cyc/step of pure LDS serialization.
// This version ingests h(t-1) with ONE ds_read_b128 per lane (own 16B
// chunk, 2-way bank alias = free) and redistributes on the VALU: 15x DPP
// row_ror:1 walks all 16 chunks past every lane; weights are pre-loaded in
// rotation order (wr[r] = own row's chunk that will be resident at rotation
// r), so every fdot2 has a compile-time register index. A one-time DPP
// direction probe (dstep) makes the ordering correct for either rotate
// convention. Per step per wave: 3 LDS ops (h-read, xe-read, h-write) vs
// R4's 6 / R6's 18. 64 fdot2 exact work, no MFMA, no select tree.
// Gate layout as R6: lane tid = row n (u = tid>>2, g = tid&3); act 1 exp2 +
// 1 rcp; 3 quad-DPPs hand f,c~,o to owner (g==0); ONE barrier per step.
__global__ __launch_bounds__(512, 2) void lstm_rec(
    const int* __restrict__ x, const float* __restrict__ emb,
    const _Float16* __restrict__ Wct, const float* __restrict__ bcat,
    _Float16* __restrict__ hbf) {
  const int b = blockIdx.x;
  const int tid = threadIdx.x;
  const int g = tid & 3;    // lane's gate (0=i,1=f,2=c,3=o)
  const int u = tid >> 2;   // lane's unit 0..127
  const int w = tid >> 6;   // wave 0..7 (e-proj phase roles)
  const int l = tid & 63;
  const int n16 = l & 15;
  const int quad = l >> 4;

  __shared__ int xrow[TT];
  __shared__ __align__(16) _Float16 comb[2][HH];   // h double-buffer
  __shared__ __align__(16) _Float16 xch[64][516];  // e-proj chunk

  xrow[tid] = x[(size_t)b * TT + tid];
  if (tid < HH) comb[0][tid] = (_Float16)0.f;

  // ---- DPP rotate-direction probe: after ror1, lane n16 holds the value of
  // lane (n16 - dstep) & 15. dstep is wave-uniform (1 or 15).
  const int pv = ror1_i(n16);
  const int dstep = (n16 - pv) & 15;

  // ---- rotation-ordered dot weights: wr[r] = W_h[row=tid][chunk c(r)],
  // c(r) = (n16 - r*dstep) & 15 — the chunk THIS lane will hold after r
  // rotations. 16 chunks x 4 h2 = 64 VGPR, loaded once (global, per-lane).
  h2 wr[16][4];
  {
    const _Float16* wp = Wct + (size_t)tid * 256 + 128;
#pragma unroll
    for (int r = 0; r < 16; ++r) {
      const int cidx = (n16 - r * dstep) & 15;
      const H2x4 q = __builtin_bit_cast(H2x4, *(const f16x8*)(wp + 8 * cidx));
      wr[r][0] = q.a;
      wr[r][1] = q.b;
      wr[r][2] = q.c;
      wr[r][3] = q.d;
    }
  }

  // per-lane activation constants: act = gam * rcp(1 + exp2(a)) + del
  const float gam = (g == 2) ? -2.f : 1.f;
  const float del = (g == 2) ? 1.f : 0.f;

  float cst = 0.f;  // valid on owner lanes (g==0) only
  float hv = 0.f;
  int buf = 0;

  __syncthreads();  // xrow + comb[0] visible

  for (int c = 0; c < 8; ++c) {
    // ---- MFMA e-projection for t in [64c,64c+64): xch[t&63][n], bias as C.
    // Operands scoped here; reload per chunk is amortized over 64 steps.
    {
      f16x8 wfx[4][4];
      f32x4 biasr[4];
#pragma unroll
      for (int nt = 0; nt < 4; ++nt) {
#pragma unroll
        for (int ks = 0; ks < 4; ++ks)
          wfx[nt][ks] =
              *(const f16x8*)(Wct + (size_t)(64 * w + nt * 16 + n16) * 256 +
                              ks * 32 + quad * 8);
        biasr[nt] = *(const f32x4*)(bcat + 64 * w + nt * 16 + quad * 4);
      }
#pragma unroll 2
      for (int tt = 0; tt < 4; ++tt) {
        const int vid = xrow[c * 64 + tt * 16 + n16];
        const float* ep = emb + (size_t)vid * HH + quad * 8;
        f16x8 ef[4];
#pragma unroll
        for (int ks = 0; ks < 4; ++ks) {
          const float4 e0 = *(const float4*)(ep + ks * 32);
          const float4 e1 = *(const float4*)(ep + ks * 32 + 4);
          H2x4 q;
          q.a = pkrtz(e0.x, e0.y);
          q.b = pkrtz(e0.z, e0.w);
          q.c = pkrtz(e1.x, e1.y);
          q.d = pkrtz(e1.z, e1.w);
          ef[ks] = __builtin_bit_cast(f16x8, q);
        }
        f32x4 acc[4];
#pragma unroll
        for (int nt = 0; nt < 4; ++nt)
          acc[nt] = __builtin_amdgcn_mfma_f32_16x16x32_f16(wfx[nt][0], ef[0],
                                                           biasr[nt], 0, 0, 0);
#pragma unroll
        for (int ks = 1; ks < 4; ++ks)
#pragma unroll
          for (int nt = 0; nt < 4; ++nt)
            acc[nt] = __builtin_amdgcn_mfma_f32_16x16x32_f16(
                wfx[nt][ks], ef[ks], acc[nt], 0, 0, 0);
#pragma unroll
        for (int nt = 0; nt < 4; ++nt) {
          _Float16* dst = &xch[tt * 16 + n16][64 * w + nt * 16 + quad * 4];
          *(h2*)dst = pkrtz(acc[nt][0], acc[nt][1]);
          *(h2*)(dst + 2) = pkrtz(acc[nt][2], acc[nt][3]);
        }
      }
    }
    __syncthreads();  // xch ready

    // ---- 64 recurrence steps
#pragma unroll 2
    for (int tl = 0; tl < 64; ++tl) {
      // lane's own-gate e-projection scalar (bias folded), 1 LDS op
      const float xe = (float)xch[tl][tid];

      // h(t-1): ONE ds_read_b128 per lane (own 16B chunk = chunk n16)
      H2x4 hq =
          __builtin_bit_cast(H2x4, *(const f16x8*)(&comb[buf][8 * n16]));

      // rotor dot: 16 x (4 fdot2 + row_ror:1); weights pre-rotation-ordered
      float s0 = 0.f, s1 = 0.f, s2 = 0.f, s3 = 0.f;
#pragma unroll
      for (int r = 0; r < 16; ++r) {
        s0 = fdot2(hq.a, wr[r][0], s0);
        s1 = fdot2(hq.b, wr[r][1], s1);
        s2 = fdot2(hq.c, wr[r][2], s2);
        s3 = fdot2(hq.d, wr[r][3], s3);
        if (r < 15) {
          hq.a = ror1_h(hq.a);
          hq.b = ror1_h(hq.b);
          hq.c = ror1_h(hq.c);
          hq.d = ror1_h(hq.d);
        }
      }
      const float a = (s0 + s1) + (s2 + s3) + xe;  // pre-activation (scaled)

      // own-gate activation: 1 exp2 + 1 rcp
      const float act = gam * frcp(1.f + fexp2(a)) + del;

      // deliver f, c~, o to the owner lane (g==0) via quad-perm DPP
      const float x1 = qmov<0xB1>(act);  // owner <- f
      const float x2 = qmov<0x4E>(act);  // owner <- c~
      const float x3 = qmov<0x4E>(x1);   // owner <- o

      // owner lanes: cst/h update (other lanes compute garbage, never used)
      cst = x1 * cst + act * x2;  // f*cst + i*c~
      const float th = 1.f - 2.f * frcp(1.f + fexp2(cst * SC_TANH));
      hv = x3 * th;

      if (g == 0) comb[buf ^ 1][u] = (_Float16)hv;  // 1 LDS op per wave
      __syncthreads();  // h(t) visible; all reads of comb[buf] done
      buf ^= 1;
    }
  }
  if (g == 0) hbf[(size_t)b * HH + u] = (_Float16)hv;
}

// logits = h @ Wout + bout via f16 MFMA, register-only.
// Block: 4 waves; tile [64 bat x 128 v]; wave: [64 bat x 32 v].
__global__ __launch_bounds__(256, 4) void lstm_out(
    const _Float16* __restrict__ Wt, const _Float16* __restrict__ hbf,
    const float* __restrict__ bout, float* __restrict__ out) {
  const int tid = threadIdx.x;
  const int wv = tid >> 6;
  const int lane = tid & 63;
  const int vblk = blockIdx.x % 250;
  const int batblk = blockIdx.x / 250;
  const int n16 = lane & 15;
  const int quad = lane >> 4;
  const int vbase = vblk * 128 + wv * 32;
  const int batbase = batblk * 64;

  f32x4 acc[4][2] = {};
#pragma unroll
  for (int ks = 0; ks < 4; ++ks) {
    const int k = ks * 32 + quad * 8;
    f16x8 a[4], bf_[2];
#pragma unroll
    for (int mt = 0; mt < 4; ++mt)
      a[mt] = *(const f16x8*)(hbf + (size_t)(batbase + mt * 16 + n16) * HH + k);
#pragma unroll
    for (int vt = 0; vt < 2; ++vt)
      bf_[vt] = *(const f16x8*)(Wt + (size_t)(vbase + vt * 16 + n16) * HH + k);
#pragma unroll
    for (int mt = 0; mt < 4; ++mt)
#pragma unroll
      for (int vt = 0; vt < 2; ++vt)
        acc[mt][vt] = __builtin_amdgcn_mfma_f32_16x16x32_f16(a[mt], bf_[vt],
                                                             acc[mt][vt], 0, 0, 0);
  }
#pragma unroll
  for (int vt = 0; vt < 2; ++vt) {
    const int v = vbase + vt * 16 + n16;
    const float bv = bout[v];
#pragma unroll
    for (int mt = 0; mt < 4; ++mt) {
#pragma unroll
      for (int r = 0; r < 4; ++r) {
        const int bat = batbase + mt * 16 + quad * 4 + r;
        out[(size_t)bat * VV + v] = acc[mt][vt][r] + bv;
      }
    }
  }
}

extern "C" void kernel_launch(void* const* d_in, const int* in_sizes, int n_in,
                              void* d_out, int out_size, void* d_ws,
                              size_t ws_size, hipStream_t stream) {
  const int* x = (const int*)d_in[0];
  const float* emb = (const float*)d_in[1];
  const float* Wi = (const float*)d_in[2];
  const float* bi = (const float*)d_in[3];
  const float* Wf = (const float*)d_in[4];
  const float* bf = (const float*)d_in[5];
  const float* Wc = (const float*)d_in[6];
  const float* bc = (const float*)d_in[7];
  const float* Wo = (const float*)d_in[8];
  const float* bo = (const float*)d_in[9];
  const float* Wout = (const float*)d_in[10];
  const float* bout = (const float*)d_in[11];
  float* out = (float*)d_out;

  _Float16* Wt = (_Float16*)d_ws;          // 32000*128 f16 = 8.192 MB
  _Float16* hbf = Wt + (size_t)VV * HH;    // 256*128 f16  = 64 KB
  _Float16* Wct = hbf + (size_t)BB * HH;   // 512*256 f16  = 256 KB
  float* bcat = (float*)(Wct + 512 * 256); // 512 f32      = 2 KB

  prep<<<512 + VV / 256, 256, 0, stream>>>(Wi, bi, Wf, bf, Wc, bc, Wo, bo,
                                           Wct, bcat, Wout, Wt);
  lstm_rec<<<BB, 512, 0, stream>>>(x, emb, Wct, bcat, hbf);
  lstm_out<<<(VV / 128) * (BB / 64), 256, 0, stream>>>(Wt, hbf, bout, out);
}

// Round 11
// 495.056 us; speedup vs baseline: 1.0384x; 1.0384x over previous
//
#include <hip/hip_runtime.h>

constexpr int TT = 512;    // timesteps
constexpr int BB = 256;    // batch
constexpr int HH = 128;    // hidden = embed
constexpr int VV = 32000;  // vocab

typedef _Float16 h2 __attribute__((ext_vector_type(2)));
typedef _Float16 f16x4 __attribute__((ext_vector_type(4)));
typedef _Float16 f16x8 __attribute__((ext_vector_type(8)));
typedef float f32x4 __attribute__((ext_vector_type(4)));

struct __align__(16) H2x4 { h2 a, b, c, d; };

__device__ __forceinline__ h2 pkrtz(float a, float b) {
  return __builtin_bit_cast(h2, __builtin_amdgcn_cvt_pkrtz(a, b));
}
__device__ __forceinline__ float fexp2(float x) {
  return __builtin_amdgcn_exp2f(x);
}
__device__ __forceinline__ float frcp(float x) {
  return __builtin_amdgcn_rcpf(x);
}
// quad_perm DPP: 0xB1 = [1,0,3,2] (xor1), 0x4E = [2,3,0,1] (xor2)
template <int CTRL>
__device__ __forceinline__ float qmov(float v) {
  return __builtin_bit_cast(
      float, __builtin_amdgcn_mov_dpp(__builtin_bit_cast(int, v), CTRL, 0xf,
                                      0xf, true));
}

// Gate pre-scales folded into weights so activations are exp2-direct:
//   g in {i,f,o}: a = -x*log2e  -> exp2(a) = e^-x   (sigmoid via rcp)
//   g == c      : a = 2x*log2e  -> exp2(a) = e^{2x} (tanh via rcp)
constexpr float SC_SIG = -1.4426950408889634f;
constexpr float SC_TANH = 2.8853900817779268f;

// Fused prep: blocks [0,512) pack gate weights into Wct[n=4u+g][k] f16
// (k 0..127 e-part, 128..255 h-part) + bcat[n] (scaled bias); blocks
// [512, 512+125) transpose Wout fp32 -> Wt[v][k] f16. One launch.
__global__ __launch_bounds__(256, 4) void prep(
    const float* __restrict__ Wi, const float* __restrict__ bi,
    const float* __restrict__ Wf, const float* __restrict__ bf,
    const float* __restrict__ Wc, const float* __restrict__ bc,
    const float* __restrict__ Wo, const float* __restrict__ bo,
    _Float16* __restrict__ Wct, float* __restrict__ bcat,
    const float* __restrict__ Wout, _Float16* __restrict__ Wt) {
  if (blockIdx.x < 512) {
    const int n = blockIdx.x;  // 0..511
    const int g = n & 3;
    const int u = n >> 2;
    const float* Wg = (g == 0) ? Wi : (g == 1) ? Wf : (g == 2) ? Wc : Wo;
    const float* bg = (g == 0) ? bi : (g == 1) ? bf : (g == 2) ? bc : bo;
    const float sc = (g == 2) ? SC_TANH : SC_SIG;
    const int k = threadIdx.x;  // 0..255
    Wct[(size_t)n * 256 + k] = (_Float16)(Wg[(size_t)k * HH + u] * sc);
    if (k == 0) bcat[n] = bg[u] * sc;
  } else {
    const int v = (blockIdx.x - 512) * 256 + threadIdx.x;
#pragma unroll 1
    for (int kc = 0; kc < 16; ++kc) {
      float f[8];
#pragma unroll
      for (int i = 0; i < 8; ++i) f[i] = Wout[(size_t)(kc * 8 + i) * VV + v];
      H2x4 q;
      q.a = pkrtz(f[0], f[1]);
      q.b = pkrtz(f[2], f[3]);
      q.c = pkrtz(f[4], f[5]);
      q.d = pkrtz(f[6], f[7]);
      *(H2x4*)(Wt + (size_t)v * HH + kc * 8) = q;
    }
  }
}

// One block per batch element (256 blocks), 1024 threads = 16 WAVES = 4/SIMD.
// R11: the untried factorial cell — MFMA-broadcast h-projection (R4's best
// structure) at 4 waves/SIMD. Per-SIMD matrix work is unchanged (32 MFMA =
// ~620 cyc/step) but split across 4 independent wave-streams (8 MFMA each):
// the matrix pipe serializes their issue, so early waves fall through to the
// activation phase while later waves still occupy the pipe — the phase
// overlap that R4's 2 phase-locked waves/SIMD could not achieve. (R8's
// 16-wave failure was dot2-specific: it doubled per-SIMD VALU+LDS work;
// here per-SIMD totals are unchanged.)
//   Wave w owns gate-rows [32w, 32w+32) = 2 MFMA tiles. Mapping follows the
//   verified R2/R3 pattern (unit = 4*nt + quad): lane (n16,quad) selects
//   tile nt=(n16>>2)&1 (4 cndmask) and gate g=n16&3 (3 cndmask), acting
//   gate g of unit u = 8w + 4*nt + quad (lanes n16>=8 duplicate). 3
//   quad-perm DPPs hand f,c~,o to owner (g==0); owner updates cst, tanh,
//   writes comb. ONE barrier per step.
// Steady-state regs ~80 (wh=32); e-proj operands scoped per chunk to stay
// under the 128-VGPR cap that 4 waves/SIMD requires.
__global__ __launch_bounds__(1024, 1) void lstm_rec(
    const int* __restrict__ x, const float* __restrict__ emb,
    const _Float16* __restrict__ Wct, const float* __restrict__ bcat,
    _Float16* __restrict__ hbf) {
  const int b = blockIdx.x;
  const int tid = threadIdx.x;
  const int w = tid >> 6;   // wave 0..15
  const int l = tid & 63;
  const int n16 = l & 15;
  const int quad = l >> 4;
  const int g = n16 & 3;                 // lane's gate (0=i,1=f,2=c,3=o)
  const int nt_sel = (n16 >> 2) & 1;     // lane's tile
  const int u = 8 * w + 4 * nt_sel + quad;  // lane's unit (dup x2 over n16>>3)
  const int xei = 4 * u + g;             // lane's e-proj column

  __shared__ int xrow[TT];
  __shared__ __align__(16) _Float16 comb[2][HH];   // h double-buffer
  __shared__ __align__(16) _Float16 xch[64][516];  // e-proj chunk

  if (tid < TT) xrow[tid] = x[(size_t)b * TT + tid];
  if (tid < HH) comb[0][tid] = (_Float16)0.f;

  // ---- h-part A-frags: wh[nt][ks], rows 32w + 16nt + n16 (32 VGPR, pinned)
  f16x8 wh[2][4];
#pragma unroll
  for (int nt = 0; nt < 2; ++nt)
#pragma unroll
    for (int ks = 0; ks < 4; ++ks)
      wh[nt][ks] = *(const f16x8*)(Wct +
                                   (size_t)(32 * w + nt * 16 + n16) * 256 +
                                   128 + ks * 32 + quad * 8);

  // per-lane activation constants: act = gam * rcp(1 + exp2(a)) + del
  const float gam = (g == 2) ? -2.f : 1.f;
  const float del = (g == 2) ? 1.f : 0.f;

  const f32x4 ZR4 = {0.f, 0.f, 0.f, 0.f};

  float cst = 0.f;  // valid on owner lanes only
  float hv = 0.f;
  int buf = 0;

  __syncthreads();  // xrow + comb[0] visible

  for (int c = 0; c < 8; ++c) {
    // ---- MFMA e-projection for t in [64c,64c+64): wave w covers cols
    // [32w, 32w+32). Operands scoped per chunk (amortized over 64 steps).
    {
      f16x8 wfx[2][4];
      f32x4 biasr[2];
#pragma unroll
      for (int nt = 0; nt < 2; ++nt) {
#pragma unroll
        for (int ks = 0; ks < 4; ++ks)
          wfx[nt][ks] =
              *(const f16x8*)(Wct + (size_t)(32 * w + nt * 16 + n16) * 256 +
                              ks * 32 + quad * 8);
        biasr[nt] = *(const f32x4*)(bcat + 32 * w + nt * 16 + quad * 4);
      }
#pragma unroll 1
      for (int tt = 0; tt < 4; ++tt) {
        const int vid = xrow[c * 64 + tt * 16 + n16];
        const float* ep = emb + (size_t)vid * HH + quad * 8;
        f16x8 ef[4];
#pragma unroll
        for (int ks = 0; ks < 4; ++ks) {
          const float4 e0 = *(const float4*)(ep + ks * 32);
          const float4 e1 = *(const float4*)(ep + ks * 32 + 4);
          H2x4 q;
          q.a = pkrtz(e0.x, e0.y);
          q.b = pkrtz(e0.z, e0.w);
          q.c = pkrtz(e1.x, e1.y);
          q.d = pkrtz(e1.z, e1.w);
          ef[ks] = __builtin_bit_cast(f16x8, q);
        }
        f32x4 acc[2];
#pragma unroll
        for (int nt = 0; nt < 2; ++nt)
          acc[nt] = __builtin_amdgcn_mfma_f32_16x16x32_f16(wfx[nt][0], ef[0],
                                                           biasr[nt], 0, 0, 0);
#pragma unroll
        for (int ks = 1; ks < 4; ++ks)
#pragma unroll
          for (int nt = 0; nt < 2; ++nt)
            acc[nt] = __builtin_amdgcn_mfma_f32_16x16x32_f16(
                wfx[nt][ks], ef[ks], acc[nt], 0, 0, 0);
#pragma unroll
        for (int nt = 0; nt < 2; ++nt) {
          _Float16* dst = &xch[tt * 16 + n16][32 * w + nt * 16 + quad * 4];
          *(h2*)dst = pkrtz(acc[nt][0], acc[nt][1]);
          *(h2*)(dst + 2) = pkrtz(acc[nt][2], acc[nt][3]);
        }
      }
    }
    __syncthreads();  // xch ready

    // ---- 64 recurrence steps
#pragma unroll 2
    for (int tl = 0; tl < 64; ++tl) {
      // lane's own-gate e-projection scalar (bias folded)
      const float xe = (float)xch[tl][xei];

      // B frags: h(t-1) broadcast to all 16 cols (wave-uniform reads)
      const _Float16* cb = comb[buf];
      f16x8 hb[4];
#pragma unroll
      for (int ks = 0; ks < 4; ++ks)
        hb[ks] = *(const f16x8*)(cb + ks * 32 + quad * 8);

      f32x4 acc0 = __builtin_amdgcn_mfma_f32_16x16x32_f16(wh[0][0], hb[0],
                                                          ZR4, 0, 0, 0);
      f32x4 acc1 = __builtin_amdgcn_mfma_f32_16x16x32_f16(wh[1][0], hb[0],
                                                          ZR4, 0, 0, 0);
#pragma unroll
      for (int ks = 1; ks < 4; ++ks) {
        acc0 = __builtin_amdgcn_mfma_f32_16x16x32_f16(wh[0][ks], hb[ks], acc0,
                                                      0, 0, 0);
        acc1 = __builtin_amdgcn_mfma_f32_16x16x32_f16(wh[1][ks], hb[ks], acc1,
                                                      0, 0, 0);
      }

      // select lane's tile (4 cndmask) and gate element (3 cndmask)
      const f32x4 avq = nt_sel ? acc1 : acc0;
      const bool s1 = (g & 1) != 0;
      const bool s2 = (g & 2) != 0;
      const float r01 = s1 ? avq[1] : avq[0];
      const float r23 = s1 ? avq[3] : avq[2];
      const float a = (s2 ? r23 : r01) + xe;  // pre-activation (scaled)

      // own-gate activation: 1 exp2 + 1 rcp
      const float act = gam * frcp(1.f + fexp2(a)) + del;

      // deliver f, c~, o to the owner lane (g==0) via quad-perm DPP
      const float x1 = qmov<0xB1>(act);  // owner <- f
      const float x2 = qmov<0x4E>(act);  // owner <- c~
      const float x3 = qmov<0x4E>(x1);   // owner <- o

      // owner lanes: cst/h update (other lanes compute garbage, never used)
      cst = x1 * cst + act * x2;  // f*cst + i*c~
      const float th = 1.f - 2.f * frcp(1.f + fexp2(cst * SC_TANH));
      hv = x3 * th;

      if (g == 0 && n16 < 8) comb[buf ^ 1][u] = (_Float16)hv;
      __syncthreads();  // h(t) visible; all reads of comb[buf] done
      buf ^= 1;
    }
  }
  if (g == 0 && n16 < 8) hbf[(size_t)b * HH + u] = (_Float16)hv;
}

// logits = h @ Wout + bout via f16 MFMA, register-only.
// Block: 4 waves; tile [64 bat x 128 v]; wave: [64 bat x 32 v].
__global__ __launch_bounds__(256, 4) void lstm_out(
    const _Float16* __restrict__ Wt, const _Float16* __restrict__ hbf,
    const float* __restrict__ bout, float* __restrict__ out) {
  const int tid = threadIdx.x;
  const int wv = tid >> 6;
  const int lane = tid & 63;
  const int vblk = blockIdx.x % 250;
  const int batblk = blockIdx.x / 250;
  const int n16 = lane & 15;
  const int quad = lane >> 4;
  const int vbase = vblk * 128 + wv * 32;
  const int batbase = batblk * 64;

  f32x4 acc[4][2] = {};
#pragma unroll
  for (int ks = 0; ks < 4; ++ks) {
    const int k = ks * 32 + quad * 8;
    f16x8 a[4], bf_[2];
#pragma unroll
    for (int mt = 0; mt < 4; ++mt)
      a[mt] = *(const f16x8*)(hbf + (size_t)(batbase + mt * 16 + n16) * HH + k);
#pragma unroll
    for (int vt = 0; vt < 2; ++vt)
      bf_[vt] = *(const f16x8*)(Wt + (size_t)(vbase + vt * 16 + n16) * HH + k);
#pragma unroll
    for (int mt = 0; mt < 4; ++mt)
#pragma unroll
      for (int vt = 0; vt < 2; ++vt)
        acc[mt][vt] = __builtin_amdgcn_mfma_f32_16x16x32_f16(a[mt], bf_[vt],
                                                             acc[mt][vt], 0, 0, 0);
  }
#pragma unroll
  for (int vt = 0; vt < 2; ++vt) {
    const int v = vbase + vt * 16 + n16;
    const float bv = bout[v];
#pragma unroll
    for (int mt = 0; mt < 4; ++mt) {
#pragma unroll
      for (int r = 0; r < 4; ++r) {
        const int bat = batbase + mt * 16 + quad * 4 + r;
        out[(size_t)bat * VV + v] = acc[mt][vt][r] + bv;
      }
    }
  }
}

extern "C" void kernel_launch(void* const* d_in, const int* in_sizes, int n_in,
                              void* d_out, int out_size, void* d_ws,
                              size_t ws_size, hipStream_t stream) {
  const int* x = (const int*)d_in[0];
  const float* emb = (const float*)d_in[1];
  const float* Wi = (const float*)d_in[2];
  const float* bi = (const float*)d_in[3];
  const float* Wf = (const float*)d_in[4];
  const float* bf = (const float*)d_in[5];
  const float* Wc = (const float*)d_in[6];
  const float* bc = (const float*)d_in[7];
  const float* Wo = (const float*)d_in[8];
  const float* bo = (const float*)d_in[9];
  const float* Wout = (const float*)d_in[10];
  const float* bout = (const float*)d_in[11];
  float* out = (float*)d_out;

  _Float16* Wt = (_Float16*)d_ws;          // 32000*128 f16 = 8.192 MB
  _Float16* hbf = Wt + (size_t)VV * HH;    // 256*128 f16  = 64 KB
  _Float16* Wct = hbf + (size_t)BB * HH;   // 512*256 f16  = 256 KB
  float* bcat = (float*)(Wct + 512 * 256); // 512 f32      = 2 KB

  prep<<<512 + VV / 256, 256, 0, stream>>>(Wi, bi, Wf, bf, Wc, bc, Wo, bo,
                                           Wct, bcat, Wout, Wt);
  lstm_rec<<<BB, 1024, 0, stream>>>(x, emb, Wct, bcat, hbf);
  lstm_out<<<(VV / 128) * (BB / 64), 256, 0, stream>>>(Wt, hbf, bout, out);
}

// Round 12
// 404.842 us; speedup vs baseline: 1.2698x; 1.2228x over previous
//
#include <hip/hip_runtime.h>

constexpr int TT = 512;    // timesteps
constexpr int BB = 256;    // batch
constexpr int HH = 128;    // hidden = embed
constexpr int VV = 32000;  // vocab

typedef _Float16 h2 __attribute__((ext_vector_type(2)));
typedef _Float16 f16x4 __attribute__((ext_vector_type(4)));
typedef _Float16 f16x8 __attribute__((ext_vector_type(8)));
typedef float f32x4 __attribute__((ext_vector_type(4)));

struct __align__(16) H2x4 { h2 a, b, c, d; };

__device__ __forceinline__ h2 pkrtz(float a, float b) {
  return __builtin_bit_cast(h2, __builtin_amdgcn_cvt_pkrtz(a, b));
}
__device__ __forceinline__ float fexp2(float x) {
  return __builtin_amdgcn_exp2f(x);
}
__device__ __forceinline__ float frcp(float x) {
  return __builtin_amdgcn_rcpf(x);
}
// quad_perm DPP: 0xB1 = [1,0,3,2] (xor1), 0x4E = [2,3,0,1] (xor2)
template <int CTRL>
__device__ __forceinline__ float qmov(float v) {
  return __builtin_bit_cast(
      float, __builtin_amdgcn_mov_dpp(__builtin_bit_cast(int, v), CTRL, 0xf,
                                      0xf, true));
}

// Gate pre-scales folded into weights so activations are exp2-direct:
//   g in {i,f,o}: a = -x*log2e  -> exp2(a) = e^-x   (sigmoid via rcp)
//   g == c      : a = 2x*log2e  -> exp2(a) = e^{2x} (tanh via rcp)
constexpr float SC_SIG = -1.4426950408889634f;
constexpr float SC_TANH = 2.8853900817779268f;

// Fused prep: blocks [0,512) pack gate weights into Wct[n=4u+g][k] f16
// (k 0..127 e-part, 128..255 h-part) + bcat[n] (scaled bias); blocks
// [512, 512+125) transpose Wout fp32 -> Wt[v][k] f16. One launch (R10-
// verified; saves a serial kernel launch vs separate wprep/wout_tr).
__global__ __launch_bounds__(256, 4) void prep(
    const float* __restrict__ Wi, const float* __restrict__ bi,
    const float* __restrict__ Wf, const float* __restrict__ bf,
    const float* __restrict__ Wc, const float* __restrict__ bc,
    const float* __restrict__ Wo, const float* __restrict__ bo,
    _Float16* __restrict__ Wct, float* __restrict__ bcat,
    const float* __restrict__ Wout, _Float16* __restrict__ Wt) {
  if (blockIdx.x < 512) {
    const int n = blockIdx.x;  // 0..511
    const int g = n & 3;
    const int u = n >> 2;
    const float* Wg = (g == 0) ? Wi : (g == 1) ? Wf : (g == 2) ? Wc : Wo;
    const float* bg = (g == 0) ? bi : (g == 1) ? bf : (g == 2) ? bc : bo;
    const float sc = (g == 2) ? SC_TANH : SC_SIG;
    const int k = threadIdx.x;  // 0..255
    Wct[(size_t)n * 256 + k] = (_Float16)(Wg[(size_t)k * HH + u] * sc);
    if (k == 0) bcat[n] = bg[u] * sc;
  } else {
    const int v = (blockIdx.x - 512) * 256 + threadIdx.x;
#pragma unroll 1
    for (int kc = 0; kc < 16; ++kc) {
      float f[8];
#pragma unroll
      for (int i = 0; i < 8; ++i) f[i] = Wout[(size_t)(kc * 8 + i) * VV + v];
      H2x4 q;
      q.a = pkrtz(f[0], f[1]);
      q.b = pkrtz(f[2], f[3]);
      q.c = pkrtz(f[4], f[5]);
      q.d = pkrtz(f[6], f[7]);
      *(H2x4*)(Wt + (size_t)v * HH + kc * 8) = q;
    }
  }
}

// R12 = R4's lstm_rec verbatim (proven 335 µs, the floor of the 8-variant
// decomposition factorial R2-R11), with one verified micro-fold: e-proj bias
// enters as the MFMA C operand (R9-R11 numerically verified) instead of a
// post-add.
// One block per batch element (256 blocks), 512 threads = 8 waves, 2/SIMD.
// Wave w owns gate-rows [64w, 64w+64) = 4 row-tiles (nt).
// Step: B = h(t-1) broadcast to 16 cols (wave-uniform ds_read_b128 x4);
//   16 MFMA (4 indep nt-chains, persistent-zero C). Lane extracts ONE scalar
//   gate g=n16&3 of unit u=16w+4*(n16>>2)+quad (15 cndmask), activates it
//   (1 exp2 + 1 rcp), 3 quad-perm DPPs hand f,c~,o to the owner lane (g==0)
//   which updates cst and does the single tanh. ONE barrier per step.
// Structural note (R2-R11 evidence): the per-step barrier phase-locks all
// waves; MFMA (~620 cyc/SIMD), VALU (~520) and LDS/latency (~430) phases do
// not overlap, and no decomposition tried (dot2, dual-pipe, rotor, 1/2/4
// waves per SIMD) beats this one. Step floor ~1570 cyc.
__global__ __launch_bounds__(512, 2) void lstm_rec(
    const int* __restrict__ x, const float* __restrict__ emb,
    const _Float16* __restrict__ Wct, const float* __restrict__ bcat,
    _Float16* __restrict__ hbf) {
  const int b = blockIdx.x;
  const int tid = threadIdx.x;
  const int w = tid >> 6;   // wave 0..7
  const int l = tid & 63;
  const int n16 = l & 15;
  const int quad = l >> 4;
  const int g = n16 & 3;                    // lane's gate (0=i,1=f,2=c,3=o)
  const int nts = n16 >> 2;                 // lane's nt slab
  const int u = 16 * w + 4 * nts + quad;    // lane's unit
  const int xcol = 4 * u + g;               // lane's e-proj column

  __shared__ int xrow[TT];
  __shared__ __align__(16) _Float16 comb[2][HH];   // h double-buffer
  __shared__ __align__(16) _Float16 xch[64][516];  // e-proj chunk

  xrow[tid] = x[(size_t)b * TT + tid];
  if (tid < HH) comb[0][tid] = (_Float16)0.f;

  // ---- h-part A-frags: wh[nt][ks], rows n = 64w + 16nt + n16 (pinned)
  f16x8 wh[4][4];
#pragma unroll
  for (int nt = 0; nt < 4; ++nt)
#pragma unroll
    for (int ks = 0; ks < 4; ++ks)
      wh[nt][ks] = *(const f16x8*)(Wct +
                                   (size_t)(64 * w + nt * 16 + n16) * 256 +
                                   128 + ks * 32 + quad * 8);

  // ---- e-part A-frags + scaled bias
  f16x8 wfx[4][4];
  f32x4 biasr[4];
#pragma unroll
  for (int nt = 0; nt < 4; ++nt) {
#pragma unroll
    for (int ks = 0; ks < 4; ++ks)
      wfx[nt][ks] = *(const f16x8*)(Wct +
                                    (size_t)(64 * w + nt * 16 + n16) * 256 +
                                    ks * 32 + quad * 8);
    biasr[nt] = *(const f32x4*)(bcat + 64 * w + nt * 16 + quad * 4);
  }

  // per-lane activation constants: act = gam * rcp(1 + exp2(a)) + del
  const float gam = (g == 2) ? -2.f : 1.f;
  const float del = (g == 2) ? 1.f : 0.f;

  const f32x4 ZR4 = {0.f, 0.f, 0.f, 0.f};

  float cst = 0.f;  // valid on owner lanes (g==0) only
  float hv = 0.f;
  int buf = 0;

  __syncthreads();  // xrow + comb[0] visible

  for (int c = 0; c < 8; ++c) {
    // ---- MFMA e-projection for t in [64c, 64c+64): xch[t&63][n], bias as C
#pragma unroll 2
    for (int tt = 0; tt < 4; ++tt) {
      const int vid = xrow[c * 64 + tt * 16 + n16];
      const float* ep = emb + (size_t)vid * HH + quad * 8;
      f16x8 ef[4];
#pragma unroll
      for (int ks = 0; ks < 4; ++ks) {
        const float4 e0 = *(const float4*)(ep + ks * 32);
        const float4 e1 = *(const float4*)(ep + ks * 32 + 4);
        H2x4 q;
        q.a = pkrtz(e0.x, e0.y);
        q.b = pkrtz(e0.z, e0.w);
        q.c = pkrtz(e1.x, e1.y);
        q.d = pkrtz(e1.z, e1.w);
        ef[ks] = __builtin_bit_cast(f16x8, q);
      }
      f32x4 acc[4];
#pragma unroll
      for (int nt = 0; nt < 4; ++nt)
        acc[nt] = __builtin_amdgcn_mfma_f32_16x16x32_f16(wfx[nt][0], ef[0],
                                                         biasr[nt], 0, 0, 0);
#pragma unroll
      for (int ks = 1; ks < 4; ++ks)
#pragma unroll
        for (int nt = 0; nt < 4; ++nt)
          acc[nt] = __builtin_amdgcn_mfma_f32_16x16x32_f16(wfx[nt][ks], ef[ks],
                                                           acc[nt], 0, 0, 0);
#pragma unroll
      for (int nt = 0; nt < 4; ++nt) {
        _Float16* dst = &xch[tt * 16 + n16][64 * w + nt * 16 + quad * 4];
        *(h2*)dst = pkrtz(acc[nt][0], acc[nt][1]);
        *(h2*)(dst + 2) = pkrtz(acc[nt][2], acc[nt][3]);
      }
    }
    __syncthreads();  // xch ready

    // ---- 64 recurrence steps
#pragma unroll 2
    for (int tl = 0; tl < 64; ++tl) {
      // lane's own-gate e-projection scalar (chunk-stable LDS, hidden
      // under the MFMA wait)
      const float xe = (float)xch[tl][xcol];

      // B frags: h(t-1) broadcast to all 16 cols (wave-uniform reads)
      const _Float16* cb = comb[buf];
      f16x8 hb[4];
#pragma unroll
      for (int ks = 0; ks < 4; ++ks)
        hb[ks] = *(const f16x8*)(cb + ks * 32 + quad * 8);

      f32x4 acc[4];
#pragma unroll
      for (int nt = 0; nt < 4; ++nt)
        acc[nt] = __builtin_amdgcn_mfma_f32_16x16x32_f16(wh[nt][0], hb[0],
                                                         ZR4, 0, 0, 0);
#pragma unroll
      for (int ks = 1; ks < 4; ++ks)
#pragma unroll
        for (int nt = 0; nt < 4; ++nt)
          acc[nt] = __builtin_amdgcn_mfma_f32_16x16x32_f16(wh[nt][ks], hb[ks],
                                                           acc[nt], 0, 0, 0);

      // extract lane's single gate scalar: nt tree (12) + r tree (3)
      const bool s4 = (n16 & 4) != 0;
      const bool s8 = (n16 & 8) != 0;
      const f32x4 t01 = s4 ? acc[1] : acc[0];
      const f32x4 t23 = s4 ? acc[3] : acc[2];
      const f32x4 avq = s8 ? t23 : t01;
      const bool s1 = (n16 & 1) != 0;
      const bool s2 = (n16 & 2) != 0;
      const float r01 = s1 ? avq[1] : avq[0];
      const float r23 = s1 ? avq[3] : avq[2];
      const float a = (s2 ? r23 : r01) + xe;  // pre-activation (scaled)

      // own-gate activation: 1 exp2 + 1 rcp per wave-lane
      const float act = gam * frcp(1.f + fexp2(a)) + del;

      // deliver f, c~, o to the owner lane (g==0) via quad-perm DPP
      const float x1 = qmov<0xB1>(act);  // owner <- f
      const float x2 = qmov<0x4E>(act);  // owner <- c~
      const float x3 = qmov<0x4E>(x1);   // owner <- o

      // owner lanes: cst/h update (other lanes compute garbage, never used)
      cst = x1 * cst + act * x2;  // f*cst + i*c~
      const float th = 1.f - 2.f * frcp(1.f + fexp2(cst * SC_TANH));
      hv = x3 * th;

      if (g == 0) comb[buf ^ 1][u] = (_Float16)hv;
      __syncthreads();  // h(t) visible; all reads of comb[buf] done
      buf ^= 1;
    }
  }
  if (g == 0) hbf[(size_t)b * HH + u] = (_Float16)hv;
}

// logits = h @ Wout + bout via f16 MFMA, register-only.
// Block: 4 waves; tile [64 bat x 128 v]; wave: [64 bat x 32 v].
__global__ __launch_bounds__(256, 4) void lstm_out(
    const _Float16* __restrict__ Wt, const _Float16* __restrict__ hbf,
    const float* __restrict__ bout, float* __restrict__ out) {
  const int tid = threadIdx.x;
  const int wv = tid >> 6;
  const int lane = tid & 63;
  const int vblk = blockIdx.x % 250;
  const int batblk = blockIdx.x / 250;
  const int n16 = lane & 15;
  const int quad = lane >> 4;
  const int vbase = vblk * 128 + wv * 32;
  const int batbase = batblk * 64;

  f32x4 acc[4][2] = {};
#pragma unroll
  for (int ks = 0; ks < 4; ++ks) {
    const int k = ks * 32 + quad * 8;
    f16x8 a[4], bf_[2];
#pragma unroll
    for (int mt = 0; mt < 4; ++mt)
      a[mt] = *(const f16x8*)(hbf + (size_t)(batbase + mt * 16 + n16) * HH + k);
#pragma unroll
    for (int vt = 0; vt < 2; ++vt)
      bf_[vt] = *(const f16x8*)(Wt + (size_t)(vbase + vt * 16 + n16) * HH + k);
#pragma unroll
    for (int mt = 0; mt < 4; ++mt)
#pragma unroll
      for (int vt = 0; vt < 2; ++vt)
        acc[mt][vt] = __builtin_amdgcn_mfma_f32_16x16x32_f16(a[mt], bf_[vt],
                                                             acc[mt][vt], 0, 0, 0);
  }
#pragma unroll
  for (int vt = 0; vt < 2; ++vt) {
    const int v = vbase + vt * 16 + n16;
    const float bv = bout[v];
#pragma unroll
    for (int mt = 0; mt < 4; ++mt) {
#pragma unroll
      for (int r = 0; r < 4; ++r) {
        const int bat = batbase + mt * 16 + quad * 4 + r;
        out[(size_t)bat * VV + v] = acc[mt][vt][r] + bv;
      }
    }
  }
}

extern "C" void kernel_launch(void* const* d_in, const int* in_sizes, int n_in,
                              void* d_out, int out_size, void* d_ws,
                              size_t ws_size, hipStream_t stream) {
  const int* x = (const int*)d_in[0];
  const float* emb = (const float*)d_in[1];
  const float* Wi = (const float*)d_in[2];
  const float* bi = (const float*)d_in[3];
  const float* Wf = (const float*)d_in[4];
  const float* bf = (const float*)d_in[5];
  const float* Wc = (const float*)d_in[6];
  const float* bc = (const float*)d_in[7];
  const float* Wo = (const float*)d_in[8];
  const float* bo = (const float*)d_in[9];
  const float* Wout = (const float*)d_in[10];
  const float* bout = (const float*)d_in[11];
  float* out = (float*)d_out;

  _Float16* Wt = (_Float16*)d_ws;          // 32000*128 f16 = 8.192 MB
  _Float16* hbf = Wt + (size_t)VV * HH;    // 256*128 f16  = 64 KB
  _Float16* Wct = hbf + (size_t)BB * HH;   // 512*256 f16  = 256 KB
  float* bcat = (float*)(Wct + 512 * 256); // 512 f32      = 2 KB

  prep<<<512 + VV / 256, 256, 0, stream>>>(Wi, bi, Wf, bf, Wc, bc, Wo, bo,
                                           Wct, bcat, Wout, Wt);
  lstm_rec<<<BB, 512, 0, stream>>>(x, emb, Wct, bcat, hbf);
  lstm_out<<<(VV / 128) * (BB / 64), 256, 0, stream>>>(Wt, hbf, bout, out);
}

// Round 13
// 404.222 us; speedup vs baseline: 1.2717x; 1.0015x over previous
//
#include <hip/hip_runtime.h>

constexpr int TT = 512;    // timesteps
constexpr int BB = 256;    // batch
constexpr int HH = 128;    // hidden = embed
constexpr int VV = 32000;  // vocab

typedef _Float16 h2 __attribute__((ext_vector_type(2)));
typedef _Float16 f16x4 __attribute__((ext_vector_type(4)));
typedef _Float16 f16x8 __attribute__((ext_vector_type(8)));
typedef float f32x4 __attribute__((ext_vector_type(4)));

struct __align__(16) H2x4 { h2 a, b, c, d; };

__device__ __forceinline__ h2 pkrtz(float a, float b) {
  return __builtin_bit_cast(h2, __builtin_amdgcn_cvt_pkrtz(a, b));
}
__device__ __forceinline__ float fexp2(float x) {
  return __builtin_amdgcn_exp2f(x);
}
__device__ __forceinline__ float frcp(float x) {
  return __builtin_amdgcn_rcpf(x);
}
// quad_perm DPP: 0xB1 = [1,0,3,2] (xor1), 0x4E = [2,3,0,1] (xor2)
template <int CTRL>
__device__ __forceinline__ float qmov(float v) {
  return __builtin_bit_cast(
      float, __builtin_amdgcn_mov_dpp(__builtin_bit_cast(int, v), CTRL, 0xf,
                                      0xf, true));
}

// Gate pre-scales folded into weights so activations are exp2-direct:
//   g in {i,f,o}: a = -x*log2e  -> exp2(a) = e^-x   (sigmoid via rcp)
//   g == c      : a = 2x*log2e  -> exp2(a) = e^{2x} (tanh via rcp)
constexpr float SC_SIG = -1.4426950408889634f;
constexpr float SC_TANH = 2.8853900817779268f;

// prep: gate-pack ONLY (R13: Wout transpose moved into lstm_rec's grid as
// co-resident filler blocks). Wct[n=4u+g][k] f16 (k 0..127 e-part, 128..255
// h-part) + bcat[n] (scaled bias).
__global__ __launch_bounds__(256, 4) void prep(
    const float* __restrict__ Wi, const float* __restrict__ bi,
    const float* __restrict__ Wf, const float* __restrict__ bf,
    const float* __restrict__ Wc, const float* __restrict__ bc,
    const float* __restrict__ Wo, const float* __restrict__ bo,
    _Float16* __restrict__ Wct, float* __restrict__ bcat) {
  const int n = blockIdx.x;  // 0..511
  const int g = n & 3;
  const int u = n >> 2;
  const float* Wg = (g == 0) ? Wi : (g == 1) ? Wf : (g == 2) ? Wc : Wo;
  const float* bg = (g == 0) ? bi : (g == 1) ? bf : (g == 2) ? bc : bo;
  const float sc = (g == 2) ? SC_TANH : SC_SIG;
  const int k = threadIdx.x;  // 0..255
  Wct[(size_t)n * 256 + k] = (_Float16)(Wg[(size_t)k * HH + u] * sc);
  if (k == 0) bcat[n] = bg[u] * sc;
}

// R13 = R12's lstm_rec core VERBATIM (proven 335 µs floor of the R2-R11
// decomposition factorial) + two orchestration changes that do not touch the
// step loop:
//   (a) blocks [256, 256+63) are Wout-transpose filler: they convert
//       Wout fp32 -> Wt f16 in the chunk-interleaved MFMA layout
//       [v16-block][kchunk][v%16][8f16] and exit. They co-reside on CUs with
//       recurrence blocks (LDS 2x68.6KB <= 160KB, 4 waves/SIMD <= 5-wave
//       VGPR cap), so their ~10 us runs inside recurrence stall slots
//       instead of as a serial prep phase.
//   (b) final h write goes to hbf in the same chunk-interleaved layout so
//       lstm_out's A-frag loads are coalesced.
// Core (unchanged): 256 blocks x 512 thr = 8 waves, 2/SIMD; wave w owns
// gate-rows [64w,64w+64); 16 MFMA vs h-broadcast; 15-cndmask gate extract;
// exp2+rcp activation; 3 quad-DPP gate exchange; ONE barrier per step.
__global__ __launch_bounds__(512, 2) void lstm_rec(
    const int* __restrict__ x, const float* __restrict__ emb,
    const _Float16* __restrict__ Wct, const float* __restrict__ bcat,
    _Float16* __restrict__ hbf, const float* __restrict__ Wout,
    _Float16* __restrict__ Wt) {
  const int tid = threadIdx.x;

  if (blockIdx.x >= BB) {
    // ---- Wout transpose filler blocks (coalesced both sides):
    // read Wout[k][v] (v = lane-contiguous), write Wt chunk
    // C(v,kc) = (v>>4)*256 + kc*16 + (v&15)  (16B chunks; lanes 0-15 ->
    // 256B contiguous).
    const int v = (blockIdx.x - BB) * 512 + tid;
    if (v < VV) {
#pragma unroll 1
      for (int kc = 0; kc < 16; ++kc) {
        float f[8];
#pragma unroll
        for (int i = 0; i < 8; ++i) f[i] = Wout[(size_t)(kc * 8 + i) * VV + v];
        H2x4 q;
        q.a = pkrtz(f[0], f[1]);
        q.b = pkrtz(f[2], f[3]);
        q.c = pkrtz(f[4], f[5]);
        q.d = pkrtz(f[6], f[7]);
        *(f16x8*)(Wt +
                  ((size_t)(v >> 4) * 256 + kc * 16 + (v & 15)) * 8) =
            __builtin_bit_cast(f16x8, q);
      }
    }
    return;
  }

  const int b = blockIdx.x;
  const int w = tid >> 6;   // wave 0..7
  const int l = tid & 63;
  const int n16 = l & 15;
  const int quad = l >> 4;
  const int g = n16 & 3;                    // lane's gate (0=i,1=f,2=c,3=o)
  const int nts = n16 >> 2;                 // lane's nt slab
  const int u = 16 * w + 4 * nts + quad;    // lane's unit
  const int xcol = 4 * u + g;               // lane's e-proj column

  __shared__ int xrow[TT];
  __shared__ __align__(16) _Float16 comb[2][HH];   // h double-buffer
  __shared__ __align__(16) _Float16 xch[64][516];  // e-proj chunk

  xrow[tid] = x[(size_t)b * TT + tid];
  if (tid < HH) comb[0][tid] = (_Float16)0.f;

  // ---- h-part A-frags: wh[nt][ks], rows n = 64w + 16nt + n16 (pinned)
  f16x8 wh[4][4];
#pragma unroll
  for (int nt = 0; nt < 4; ++nt)
#pragma unroll
    for (int ks = 0; ks < 4; ++ks)
      wh[nt][ks] = *(const f16x8*)(Wct +
                                   (size_t)(64 * w + nt * 16 + n16) * 256 +
                                   128 + ks * 32 + quad * 8);

  // ---- e-part A-frags + scaled bias
  f16x8 wfx[4][4];
  f32x4 biasr[4];
#pragma unroll
  for (int nt = 0; nt < 4; ++nt) {
#pragma unroll
    for (int ks = 0; ks < 4; ++ks)
      wfx[nt][ks] = *(const f16x8*)(Wct +
                                    (size_t)(64 * w + nt * 16 + n16) * 256 +
                                    ks * 32 + quad * 8);
    biasr[nt] = *(const f32x4*)(bcat + 64 * w + nt * 16 + quad * 4);
  }

  // per-lane activation constants: act = gam * rcp(1 + exp2(a)) + del
  const float gam = (g == 2) ? -2.f : 1.f;
  const float del = (g == 2) ? 1.f : 0.f;

  const f32x4 ZR4 = {0.f, 0.f, 0.f, 0.f};

  float cst = 0.f;  // valid on owner lanes (g==0) only
  float hv = 0.f;
  int buf = 0;

  __syncthreads();  // xrow + comb[0] visible

  for (int c = 0; c < 8; ++c) {
    // ---- MFMA e-projection for t in [64c, 64c+64): xch[t&63][n], bias as C
#pragma unroll 2
    for (int tt = 0; tt < 4; ++tt) {
      const int vid = xrow[c * 64 + tt * 16 + n16];
      const float* ep = emb + (size_t)vid * HH + quad * 8;
      f16x8 ef[4];
#pragma unroll
      for (int ks = 0; ks < 4; ++ks) {
        const float4 e0 = *(const float4*)(ep + ks * 32);
        const float4 e1 = *(const float4*)(ep + ks * 32 + 4);
        H2x4 q;
        q.a = pkrtz(e0.x, e0.y);
        q.b = pkrtz(e0.z, e0.w);
        q.c = pkrtz(e1.x, e1.y);
        q.d = pkrtz(e1.z, e1.w);
        ef[ks] = __builtin_bit_cast(f16x8, q);
      }
      f32x4 acc[4];
#pragma unroll
      for (int nt = 0; nt < 4; ++nt)
        acc[nt] = __builtin_amdgcn_mfma_f32_16x16x32_f16(wfx[nt][0], ef[0],
                                                         biasr[nt], 0, 0, 0);
#pragma unroll
      for (int ks = 1; ks < 4; ++ks)
#pragma unroll
        for (int nt = 0; nt < 4; ++nt)
          acc[nt] = __builtin_amdgcn_mfma_f32_16x16x32_f16(wfx[nt][ks], ef[ks],
                                                           acc[nt], 0, 0, 0);
#pragma unroll
      for (int nt = 0; nt < 4; ++nt) {
        _Float16* dst = &xch[tt * 16 + n16][64 * w + nt * 16 + quad * 4];
        *(h2*)dst = pkrtz(acc[nt][0], acc[nt][1]);
        *(h2*)(dst + 2) = pkrtz(acc[nt][2], acc[nt][3]);
      }
    }
    __syncthreads();  // xch ready

    // ---- 64 recurrence steps
#pragma unroll 2
    for (int tl = 0; tl < 64; ++tl) {
      // lane's own-gate e-projection scalar
      const float xe = (float)xch[tl][xcol];

      // B frags: h(t-1) broadcast to all 16 cols (wave-uniform reads)
      const _Float16* cb = comb[buf];
      f16x8 hb[4];
#pragma unroll
      for (int ks = 0; ks < 4; ++ks)
        hb[ks] = *(const f16x8*)(cb + ks * 32 + quad * 8);

      f32x4 acc[4];
#pragma unroll
      for (int nt = 0; nt < 4; ++nt)
        acc[nt] = __builtin_amdgcn_mfma_f32_16x16x32_f16(wh[nt][0], hb[0],
                                                         ZR4, 0, 0, 0);
#pragma unroll
      for (int ks = 1; ks < 4; ++ks)
#pragma unroll
        for (int nt = 0; nt < 4; ++nt)
          acc[nt] = __builtin_amdgcn_mfma_f32_16x16x32_f16(wh[nt][ks], hb[ks],
                                                           acc[nt], 0, 0, 0);

      // extract lane's single gate scalar: nt tree (12) + r tree (3)
      const bool s4 = (n16 & 4) != 0;
      const bool s8 = (n16 & 8) != 0;
      const f32x4 t01 = s4 ? acc[1] : acc[0];
      const f32x4 t23 = s4 ? acc[3] : acc[2];
      const f32x4 avq = s8 ? t23 : t01;
      const bool s1 = (n16 & 1) != 0;
      const bool s2 = (n16 & 2) != 0;
      const float r01 = s1 ? avq[1] : avq[0];
      const float r23 = s1 ? avq[3] : avq[2];
      const float a = (s2 ? r23 : r01) + xe;  // pre-activation (scaled)

      // own-gate activation: 1 exp2 + 1 rcp per wave-lane
      const float act = gam * frcp(1.f + fexp2(a)) + del;

      // deliver f, c~, o to the owner lane (g==0) via quad-perm DPP
      const float x1 = qmov<0xB1>(act);  // owner <- f
      const float x2 = qmov<0x4E>(act);  // owner <- c~
      const float x3 = qmov<0x4E>(x1);   // owner <- o

      // owner lanes: cst/h update (other lanes compute garbage, never used)
      cst = x1 * cst + act * x2;  // f*cst + i*c~
      const float th = 1.f - 2.f * frcp(1.f + fexp2(cst * SC_TANH));
      hv = x3 * th;

      if (g == 0) comb[buf ^ 1][u] = (_Float16)hv;
      __syncthreads();  // h(t) visible; all reads of comb[buf] done
      buf ^= 1;
    }
  }
  // chunk-interleaved hbf: C(bat,kc) = (bat>>4)*256 + kc*16 + (bat&15),
  // elem u&7 within the 8-f16 chunk (kc = u>>3).
  if (g == 0)
    hbf[((size_t)(b >> 4) * 256 + (u >> 3) * 16 + (b & 15)) * 8 + (u & 7)] =
        (_Float16)hv;
}

// logits = h @ Wout + bout via f16 MFMA. R13: both operand matrices are in
// chunk-interleaved layout [row16][kchunk][row%16][8f16], so each frag load
// reads 64 CONSECUTIVE 16B chunks per wave (1KB contiguous) instead of the
// previous 256B-stride gather (64 cache lines / 4x over-fetch per instr).
// Block: 4 waves; tile [64 bat x 128 v]; wave: [64 bat x 32 v].
__global__ __launch_bounds__(256, 4) void lstm_out(
    const _Float16* __restrict__ Wt, const _Float16* __restrict__ hbf,
    const float* __restrict__ bout, float* __restrict__ out) {
  const int tid = threadIdx.x;
  const int wv = tid >> 6;
  const int lane = tid & 63;
  const int vblk = blockIdx.x % 250;
  const int batblk = blockIdx.x / 250;
  const int n16 = lane & 15;
  const int quad = lane >> 4;
  const int vbase = vblk * 128 + wv * 32;
  const int batbase = batblk * 64;

  f32x4 acc[4][2] = {};
#pragma unroll
  for (int ks = 0; ks < 4; ++ks) {
    f16x8 a[4], bf_[2];
#pragma unroll
    for (int mt = 0; mt < 4; ++mt)
      a[mt] = *(const f16x8*)(hbf +
                              (((size_t)(batblk * 4 + mt) << 8) + (ks << 6) +
                               lane) * 8);
#pragma unroll
    for (int vt = 0; vt < 2; ++vt)
      bf_[vt] = *(const f16x8*)(Wt +
                                (((size_t)(vblk * 8 + wv * 2 + vt) << 8) +
                                 (ks << 6) + lane) * 8);
#pragma unroll
    for (int mt = 0; mt < 4; ++mt)
#pragma unroll
      for (int vt = 0; vt < 2; ++vt)
        acc[mt][vt] = __builtin_amdgcn_mfma_f32_16x16x32_f16(a[mt], bf_[vt],
                                                             acc[mt][vt], 0, 0, 0);
  }
#pragma unroll
  for (int vt = 0; vt < 2; ++vt) {
    const int v = vbase + vt * 16 + n16;
    const float bv = bout[v];
#pragma unroll
    for (int mt = 0; mt < 4; ++mt) {
#pragma unroll
      for (int r = 0; r < 4; ++r) {
        const int bat = batbase + mt * 16 + quad * 4 + r;
        out[(size_t)bat * VV + v] = acc[mt][vt][r] + bv;
      }
    }
  }
}

extern "C" void kernel_launch(void* const* d_in, const int* in_sizes, int n_in,
                              void* d_out, int out_size, void* d_ws,
                              size_t ws_size, hipStream_t stream) {
  const int* x = (const int*)d_in[0];
  const float* emb = (const float*)d_in[1];
  const float* Wi = (const float*)d_in[2];
  const float* bi = (const float*)d_in[3];
  const float* Wf = (const float*)d_in[4];
  const float* bf = (const float*)d_in[5];
  const float* Wc = (const float*)d_in[6];
  const float* bc = (const float*)d_in[7];
  const float* Wo = (const float*)d_in[8];
  const float* bo = (const float*)d_in[9];
  const float* Wout = (const float*)d_in[10];
  const float* bout = (const float*)d_in[11];
  float* out = (float*)d_out;

  _Float16* Wt = (_Float16*)d_ws;          // 32000*128 f16 = 8.192 MB
  _Float16* hbf = Wt + (size_t)VV * HH;    // 256*128 f16  = 64 KB
  _Float16* Wct = hbf + (size_t)BB * HH;   // 512*256 f16  = 256 KB
  float* bcat = (float*)(Wct + 512 * 256); // 512 f32      = 2 KB

  prep<<<512, 256, 0, stream>>>(Wi, bi, Wf, bf, Wc, bc, Wo, bo, Wct, bcat);
  // 256 recurrence blocks + 63 co-resident Wout-transpose filler blocks
  lstm_rec<<<BB + 63, 512, 0, stream>>>(x, emb, Wct, bcat, hbf, Wout, Wt);
  lstm_out<<<(VV / 128) * (BB / 64), 256, 0, stream>>>(Wt, hbf, bout, out);
}